// Round 4
// baseline (158.286 us; speedup 1.0000x reference)
//
#include <hip/hip_runtime.h>

#define Bn 4
#define Cdim 64
#define INTER 32
#define Ln 4096
#define LOG2E 1.44269504088896340736f

typedef _Float16 half_t;
typedef __attribute__((ext_vector_type(2))) _Float16 half2v;
typedef __attribute__((ext_vector_type(8))) _Float16 half8v;
typedef __attribute__((ext_vector_type(4))) short short4v;
typedef __attribute__((ext_vector_type(4))) float f32x4;

__device__ __forceinline__ unsigned short f2bf(float f) {
    unsigned u = __float_as_uint(f);
    u += 0x7fffu + ((u >> 16) & 1u);
    return (unsigned short)(u >> 16);
}
__device__ __forceinline__ float bf2f(unsigned short b) {
    return __uint_as_float(((unsigned)b) << 16);
}
// pack bf16(a) low16, bf16(b) high16 (round-half-up)
__device__ __forceinline__ unsigned pack_bf(float a, float b) {
    unsigned ua = __float_as_uint(a) + 0x8000u;
    unsigned ub = __float_as_uint(b) + 0x8000u;
    return __builtin_amdgcn_perm(ub, ua, 0x07060302);
}

// ---------------------------------------------------------------------------
// setup: Wcat f16[128][64] = [th_w*log2e ; ph_w ; W_w*g_w],
// biasbuf f32[128] = [th_b*log2e ; ph_b ; 0], bc f32[64] = W_w*g_b + W_b
// ---------------------------------------------------------------------------
__global__ void setup_kernel(const float* __restrict__ g_w, const float* __restrict__ g_b,
                             const float* __restrict__ th_w, const float* __restrict__ th_b,
                             const float* __restrict__ ph_w, const float* __restrict__ ph_b,
                             const float* __restrict__ W_w, const float* __restrict__ W_b,
                             half_t* __restrict__ Wcat, float* __restrict__ biasbuf,
                             float* __restrict__ bc) {
    int blk = blockIdx.x, tid = threadIdx.x;
    if (blk < 128) {
        int row = blk, c = tid;
        float v;
        if (row < 32) v = th_w[row * 64 + c] * LOG2E;
        else if (row < 64) v = ph_w[(row - 32) * 64 + c];
        else {
            int cc = row - 64;
            v = 0.f;
            for (int j = 0; j < 32; j++) v = fmaf(W_w[cc * 32 + j], g_w[j * 64 + c], v);
        }
        Wcat[row * 64 + c] = (half_t)v;
    } else if (blk == 128) {
        float v0 = (tid < 32) ? th_b[tid] * LOG2E : ph_b[tid - 32];
        biasbuf[tid] = v0;
        biasbuf[64 + tid] = 0.f;
    } else {
        float v = W_b[tid];
        for (int j = 0; j < 32; j++) v = fmaf(W_w[tid * 32 + j], g_b[j], v);
        bc[tid] = v;
    }
}

// ---------------------------------------------------------------------------
// proj as MFMA GEMM: out[128ch][64l-tile] = Wcat[128][64c] * x[64c][l-tile].
// Block 256 thr / 4 waves; wave grp handles 32 ch. Grid Bn*64.
// theta/phi f16 [l][32] (via LDS transpose), gT bf16 [c][l].
// ---------------------------------------------------------------------------
__global__ __launch_bounds__(256) void proj_kernel(
        const float* __restrict__ x, const half_t* __restrict__ Wcat,
        const float* __restrict__ biasbuf,
        half_t* __restrict__ theta, half_t* __restrict__ phi,
        unsigned short* __restrict__ gT) {
    __shared__ half_t sx[64][72];        // [l][c], 144B rows (16B-aligned)
    __shared__ half_t tbuf[2][64][36];   // theta/phi transpose staging

    int tid = threadIdx.x;
    int b = blockIdx.x >> 6;
    int l0 = (blockIdx.x & 63) << 6;

    // stage x tile: thread (lx, cq): 16 c's for one l; coalesced 256B row loads
    int lx = tid & 63, cq = tid >> 6;
    {
        const float* xb = x + (size_t)(b * 64 + cq * 16) * Ln + l0 + lx;
#pragma unroll
        for (int j = 0; j < 4; j++) {
            float v0 = xb[(size_t)(4 * j + 0) * Ln];
            float v1 = xb[(size_t)(4 * j + 1) * Ln];
            float v2 = xb[(size_t)(4 * j + 2) * Ln];
            float v3 = xb[(size_t)(4 * j + 3) * Ln];
            half2v h0; h0.x = (half_t)v0; h0.y = (half_t)v1;
            half2v h1; h1.x = (half_t)v2; h1.y = (half_t)v3;
            half2v* dst = (half2v*)&sx[lx][cq * 16 + 4 * j];
            dst[0] = h0; dst[1] = h1;
        }
    }
    __syncthreads();

    int lane = tid & 63, grp = tid >> 6;
    int l15 = lane & 15, quad = lane >> 4;

    // A-frags: Wcat rows (m = ch)
    half8v wA[2][2];
#pragma unroll
    for (int mf = 0; mf < 2; mf++)
#pragma unroll
        for (int kk = 0; kk < 2; kk++)
            wA[mf][kk] = *(const half8v*)(Wcat + (grp * 32 + mf * 16 + l15) * 64 +
                                          kk * 32 + quad * 8);
    // B-frags: x tile (n = l)
    half8v xB[4][2];
#pragma unroll
    for (int nf = 0; nf < 4; nf++)
#pragma unroll
        for (int kk = 0; kk < 2; kk++)
            xB[nf][kk] = *(const half8v*)&sx[nf * 16 + l15][kk * 32 + quad * 8];

    f32x4 acc[2][4];
    const f32x4 z = {0.f, 0.f, 0.f, 0.f};
#pragma unroll
    for (int mf = 0; mf < 2; mf++)
#pragma unroll
        for (int nf = 0; nf < 4; nf++) {
            f32x4 a = __builtin_amdgcn_mfma_f32_16x16x32_f16(wA[mf][0], xB[nf][0], z, 0, 0, 0);
            acc[mf][nf] = __builtin_amdgcn_mfma_f32_16x16x32_f16(wA[mf][1], xB[nf][1], a, 0, 0, 0);
        }

    // bias (rows 64..127 are zero)
#pragma unroll
    for (int mf = 0; mf < 2; mf++) {
        float4 bv = *(const float4*)&biasbuf[grp * 32 + mf * 16 + quad * 4];
#pragma unroll
        for (int nf = 0; nf < 4; nf++) {
            acc[mf][nf][0] += bv.x; acc[mf][nf][1] += bv.y;
            acc[mf][nf][2] += bv.z; acc[mf][nf][3] += bv.w;
        }
    }

    if (grp < 2) {
        // theta/phi: transpose to [l][32] via wave-private LDS buffer
#pragma unroll
        for (int mf = 0; mf < 2; mf++)
#pragma unroll
            for (int nf = 0; nf < 4; nf++) {
                half2v h0; h0.x = (half_t)acc[mf][nf][0]; h0.y = (half_t)acc[mf][nf][1];
                half2v h1; h1.x = (half_t)acc[mf][nf][2]; h1.y = (half_t)acc[mf][nf][3];
                half2v* dst = (half2v*)&tbuf[grp][nf * 16 + l15][mf * 16 + quad * 4];
                dst[0] = h0; dst[1] = h1;
            }
        half_t* out = (grp == 0) ? theta : phi;
        half_t* orow = out + ((size_t)(b * Ln + l0 + lane)) * 32;
#pragma unroll
        for (int i = 0; i < 4; i++) {
            float4 v = *(const float4*)&tbuf[grp][lane][i * 8];
            *(float4*)&orow[i * 8] = v;
        }
    } else {
        int cg = grp - 2;
#pragma unroll
        for (int mf = 0; mf < 2; mf++)
#pragma unroll
            for (int nf = 0; nf < 4; nf++)
#pragma unroll
                for (int r = 0; r < 4; r++) {
                    int c = cg * 32 + mf * 16 + quad * 4 + r;
                    gT[((size_t)(b * 64 + c)) * Ln + l0 + nf * 16 + l15] =
                        f2bf(acc[mf][nf][r]);
                }
    }
}

// ---------------------------------------------------------------------------
// attn: S' = phi*theta^T (16x16x32 f16, C: col=q, row=key) -> exp2 -> packed
// bf16 pairs feed 16x16x16_bf16 PV DIRECTLY as B operand (layouts match).
// No LDS in the loop. Partials unnormalized. Grid Bn*32*KC, 4 blocks/CU.
// ---------------------------------------------------------------------------
__global__ __launch_bounds__(256, 4) void attn_kernel(
        const half_t* __restrict__ theta, const half_t* __restrict__ phi,
        const unsigned short* __restrict__ gT,
        unsigned short* __restrict__ part, float* __restrict__ Sden,
        int KC, int CH) {
    int tid = threadIdx.x;
    int lane = tid & 63, widx = tid >> 6;
    int l15 = lane & 15, quad = lane >> 4;

    int blk = blockIdx.x;
    int b = blk / (32 * KC);
    int rem = blk % (32 * KC);
    int qblk = rem / KC;
    int kc = rem % KC;
    int qbase = qblk * 128 + widx * 32;
    int k0 = kc * CH;

    // theta B-frags (n=q, k=c): persistent
    half8v th[2];
#pragma unroll
    for (int qf = 0; qf < 2; qf++)
        th[qf] = *(const half8v*)(theta + ((size_t)(b * Ln + qbase + qf * 16 + l15)) * 32 +
                                  quad * 8);

    f32x4 acc[2][4];
#pragma unroll
    for (int qf = 0; qf < 2; qf++)
#pragma unroll
        for (int cf = 0; cf < 4; cf++) acc[qf][cf] = (f32x4){0.f, 0.f, 0.f, 0.f};
    float lsum[2] = {0.f, 0.f};

    const half_t* phib = phi + (size_t)b * Ln * 32;
    const unsigned short* gTb = gT + (size_t)b * Cdim * Ln;
    const f32x4 z = {0.f, 0.f, 0.f, 0.f};

    // prefetch first phi A-frags (m=key, k=c)
    half8v ph_c[4];
#pragma unroll
    for (int kf = 0; kf < 4; kf++)
        ph_c[kf] = *(const half8v*)(phib + ((size_t)(k0 + kf * 16 + l15)) * 32 + quad * 8);

    for (int kt = k0; kt < k0 + CH; kt += 64) {
        // gT A-frags for PV (m=c, k=key, K=16): 8B dwordx2 each
        short4v ga[4][4];
#pragma unroll
        for (int kf = 0; kf < 4; kf++)
#pragma unroll
            for (int cf = 0; cf < 4; cf++)
                ga[kf][cf] = *(const short4v*)(gTb + ((size_t)(cf * 16 + l15)) * Ln +
                                               kt + kf * 16 + quad * 4);
        // prefetch next phi frags
        half8v ph_n[4];
        if (kt + 64 < k0 + CH) {
#pragma unroll
            for (int kf = 0; kf < 4; kf++)
                ph_n[kf] = *(const half8v*)(phib + ((size_t)(kt + 64 + kf * 16 + l15)) * 32 +
                                            quad * 8);
        }

#pragma unroll
        for (int kf = 0; kf < 4; kf++) {
#pragma unroll
            for (int qf = 0; qf < 2; qf++) {
                f32x4 s = __builtin_amdgcn_mfma_f32_16x16x32_f16(ph_c[kf], th[qf], z, 0, 0, 0);
                float p0 = __builtin_amdgcn_exp2f(s[0]);
                float p1 = __builtin_amdgcn_exp2f(s[1]);
                float p2 = __builtin_amdgcn_exp2f(s[2]);
                float p3 = __builtin_amdgcn_exp2f(s[3]);
                lsum[qf] += (p0 + p1) + (p2 + p3);
                union { short4v s4; uint2 u2; } pb;
                pb.u2.x = pack_bf(p0, p1);
                pb.u2.y = pack_bf(p2, p3);
                // PV: y^T[c][q] += gT-frag * P-frag (B operand = packed P, direct)
#pragma unroll
                for (int cf = 0; cf < 4; cf++)
                    acc[qf][cf] = __builtin_amdgcn_mfma_f32_16x16x16bf16_1k(
                        ga[kf][cf], pb.s4, acc[qf][cf], 0, 0, 0);
            }
        }
#pragma unroll
        for (int kf = 0; kf < 4; kf++) ph_c[kf] = ph_n[kf];
    }

    // denominator: lane holds partial for q=l15 over its quad's keys
#pragma unroll
    for (int qf = 0; qf < 2; qf++) {
        float v = lsum[qf];
        v += __shfl_xor(v, 16);
        v += __shfl_xor(v, 32);
        lsum[qf] = v;
    }
    size_t sbase = ((size_t)(b * KC + kc)) * Ln + qbase;
    if (lane < 16) {
        Sden[sbase + lane] = lsum[0];
        Sden[sbase + 16 + lane] = lsum[1];
    }

    // part store: lane (l15,quad) holds y for q=qf*16+l15, c=cf*16+quad*4+r
    size_t pbase = ((size_t)(b * KC + kc)) * Cdim * Ln;
#pragma unroll
    for (int qf = 0; qf < 2; qf++)
#pragma unroll
        for (int cf = 0; cf < 4; cf++)
#pragma unroll
            for (int r = 0; r < 4; r++) {
                int c = cf * 16 + quad * 4 + r;
                part[pbase + (size_t)c * Ln + qbase + qf * 16 + l15] =
                    f2bf(acc[qf][cf][r]);
            }
}

// ---------------------------------------------------------------------------
// merge: out = sum_kc(part)/sum_kc(Sden) + bc[c] + x
// ---------------------------------------------------------------------------
__global__ __launch_bounds__(256) void merge_kernel(
        const unsigned short* __restrict__ part, const float* __restrict__ Sden,
        const float* __restrict__ bc, const float* __restrict__ x,
        float* __restrict__ out, int KC) {
    int t = blockIdx.x * 256 + threadIdx.x;
    int l4 = (t & 1023) << 2;
    int c = (t >> 10) & 63;
    int b = t >> 16;
    float4 num = {0.f, 0.f, 0.f, 0.f};
    float4 den = {0.f, 0.f, 0.f, 0.f};
    for (int kc = 0; kc < KC; kc++) {
        const unsigned short* pp =
            part + ((size_t)(b * KC + kc)) * Cdim * Ln + (size_t)c * Ln + l4;
        ushort4 y4 = *(const ushort4*)pp;
        float4 lc = *(const float4*)&Sden[((size_t)(b * KC + kc)) * Ln + l4];
        num.x += bf2f(y4.x); num.y += bf2f(y4.y);
        num.z += bf2f(y4.z); num.w += bf2f(y4.w);
        den.x += lc.x; den.y += lc.y; den.z += lc.z; den.w += lc.w;
    }
    float bias = bc[c];
    size_t xi = (size_t)t * 4;
    float4 xv = *(const float4*)&x[xi];
    float4 o;
    o.x = num.x / den.x + bias + xv.x;
    o.y = num.y / den.y + bias + xv.y;
    o.z = num.z / den.z + bias + xv.z;
    o.w = num.w / den.w + bias + xv.w;
    *(float4*)&out[xi] = o;
}

extern "C" void kernel_launch(void* const* d_in, const int* in_sizes, int n_in,
                              void* d_out, int out_size, void* d_ws, size_t ws_size,
                              hipStream_t stream) {
    const float* x    = (const float*)d_in[0];
    const float* g_w  = (const float*)d_in[1];
    const float* g_b  = (const float*)d_in[2];
    const float* th_w = (const float*)d_in[3];
    const float* th_b = (const float*)d_in[4];
    const float* ph_w = (const float*)d_in[5];
    const float* ph_b = (const float*)d_in[6];
    const float* W_w  = (const float*)d_in[7];
    const float* W_b  = (const float*)d_in[8];
    float* out = (float*)d_out;

    char* w = (char*)d_ws;
    const size_t off_theta = 0;
    const size_t off_phi   = 1048576;           // 4*4096*32*2
    const size_t off_gT    = 2097152;           // 4*64*4096*2
    const size_t off_Wcat  = 4194304;           // 128*64*2
    const size_t off_bias  = 4210688;           // 128*4
    const size_t off_bc    = 4211200;           // 64*4
    const size_t off_Sden  = 4211456;           // 16B aligned

    int KC = 8;
    size_t off_part = 0;
    while (true) {
        off_part = off_Sden + (size_t)KC * (Bn * Ln * 4);
        off_part = (off_part + 255) & ~(size_t)255;
        size_t need = off_part + (size_t)KC * ((size_t)Bn * Cdim * Ln * 2);
        if (need <= ws_size || KC == 1) break;
        KC >>= 1;
    }

    half_t* theta = (half_t*)(w + off_theta);
    half_t* phi   = (half_t*)(w + off_phi);
    unsigned short* gT = (unsigned short*)(w + off_gT);
    half_t* Wcat  = (half_t*)(w + off_Wcat);
    float* biasbuf = (float*)(w + off_bias);
    float* bc     = (float*)(w + off_bc);
    float* Sden   = (float*)(w + off_Sden);
    unsigned short* part = (unsigned short*)(w + off_part);

    int CH = Ln / KC;

    setup_kernel<<<130, 64, 0, stream>>>(g_w, g_b, th_w, th_b, ph_w, ph_b, W_w, W_b,
                                         Wcat, biasbuf, bc);
    proj_kernel<<<Bn * 64, 256, 0, stream>>>(x, Wcat, biasbuf, theta, phi, gT);
    attn_kernel<<<Bn * 32 * KC, 256, 0, stream>>>(theta, phi, gT, part, Sden, KC, CH);
    merge_kernel<<<Bn * Cdim * Ln / 1024, 256, 0, stream>>>(part, Sden, bc, x, out, KC);
}

// Round 5
// 104.635 us; speedup vs baseline: 1.5127x; 1.5127x over previous
//
#include <hip/hip_runtime.h>

#define Bn 4
#define Cdim 64
#define INTER 32
#define Ln 4096
#define LOG2E 1.44269504088896340736f

typedef _Float16 half_t;
typedef __attribute__((ext_vector_type(8))) _Float16 half8v;
typedef __attribute__((ext_vector_type(4))) short short4v;
typedef __attribute__((ext_vector_type(8))) short short8v;
typedef __attribute__((ext_vector_type(4))) float f32x4;

__device__ __forceinline__ unsigned short f2bf(float f) {
    unsigned u = __float_as_uint(f);
    u += 0x7fffu + ((u >> 16) & 1u);
    return (unsigned short)(u >> 16);
}
__device__ __forceinline__ float bf2f(unsigned short b) {
    return __uint_as_float(((unsigned)b) << 16);
}
__device__ __forceinline__ unsigned pack_bf(float a, float b) {
    unsigned ua = __float_as_uint(a) + 0x8000u;
    unsigned ub = __float_as_uint(b) + 0x8000u;
    return __builtin_amdgcn_perm(ub, ua, 0x07060302);
}
__device__ __forceinline__ void gll16(const void* g, void* l) {
    __builtin_amdgcn_global_load_lds(
        (const __attribute__((address_space(1))) unsigned int*)g,
        (__attribute__((address_space(3))) unsigned int*)l, 16, 0, 0);
}

// ---------------------------------------------------------------------------
// setup: Wcat f16[96][64] = [th_w*log2e ; ph_w ; g_w]; biasbuf f32[96] =
// [th_b*log2e ; ph_b ; g_b]; bc f32[64] = W_b; Wm = W_w f16 in MFMA A-frag
// layout (4 mf-tiles x 64 lanes x 8 halves). Grid 99 x 64.
// ---------------------------------------------------------------------------
__global__ void setup_kernel(const float* __restrict__ g_w, const float* __restrict__ g_b,
                             const float* __restrict__ th_w, const float* __restrict__ th_b,
                             const float* __restrict__ ph_w, const float* __restrict__ ph_b,
                             const float* __restrict__ W_w, const float* __restrict__ W_b,
                             half_t* __restrict__ Wcat, float* __restrict__ biasbuf,
                             float* __restrict__ bc, half_t* __restrict__ Wm) {
    int blk = blockIdx.x, tid = threadIdx.x;
    if (blk < 96) {
        int row = blk;
        float v;
        if (row < 32) v = th_w[row * 64 + tid] * LOG2E;
        else if (row < 64) v = ph_w[(row - 32) * 64 + tid];
        else v = g_w[(row - 64) * 64 + tid];
        Wcat[row * 64 + tid] = (half_t)v;
    } else if (blk == 96) {
        for (int i = tid; i < 96; i += 64) {
            float v = (i < 32) ? th_b[i] * LOG2E : (i < 64) ? ph_b[i - 32] : g_b[i - 64];
            biasbuf[i] = v;
        }
    } else if (blk == 97) {
        bc[tid] = W_b[tid];
    } else {
        // Wm A-frags: lane(l15,quad) of tile mf holds W[c=mf*16+l15][k=quad*8+j]
        int l15 = tid & 15, jb = (tid >> 4) * 8;
        for (int mf = 0; mf < 4; mf++) {
            int c = mf * 16 + l15;
            half_t tmp[8];
            for (int j = 0; j < 8; j++) tmp[j] = (half_t)W_w[c * 32 + jb + j];
            float4 v;
            __builtin_memcpy(&v, tmp, 16);
            *(float4*)(Wm + (mf * 64 + tid) * 8) = v;
        }
    }
}

// ---------------------------------------------------------------------------
// proj (MFMA): [96ch][64l] = Wcat * x-tile. Grid Bn*64 x 192 (3 waves).
// Outputs written directly in MFMA *fragment* layout:
//   thfrag/phfrag: [b][l16][lane][8 f16]  (A/B-frag for 16x16x32, k=INTER)
//   gfrag:         [b][k16][lane][8 bf16] (A-frag for 16x16x16 PV; 16B unit =
//                  [c=l15, keys quad*4..+3 | c=16+l15, same keys])
// ---------------------------------------------------------------------------
__global__ __launch_bounds__(192) void proj_kernel(
        const float* __restrict__ x, const half_t* __restrict__ Wcat,
        const float* __restrict__ biasbuf,
        half_t* __restrict__ thfrag, half_t* __restrict__ phfrag,
        unsigned short* __restrict__ gfrag) {
    __shared__ half_t sx[64][72];   // [l][c], 144B rows (16B-multiple)
    int tid = threadIdx.x;
    int b = blockIdx.x >> 6;
    int l0 = (blockIdx.x & 63) << 6;

    for (int i = tid; i < 1024; i += 192) {
        int c = i >> 4, lq = (i & 15) << 2;
        float4 v = *(const float4*)&x[(size_t)(b * 64 + c) * Ln + l0 + lq];
        sx[lq + 0][c] = (half_t)v.x;
        sx[lq + 1][c] = (half_t)v.y;
        sx[lq + 2][c] = (half_t)v.z;
        sx[lq + 3][c] = (half_t)v.w;
    }
    __syncthreads();

    int lane = tid & 63, grp = tid >> 6;    // grp: 0=theta 1=phi 2=g
    int l15 = lane & 15, quad = lane >> 4;

    half8v wA[2][2];
#pragma unroll
    for (int mf = 0; mf < 2; mf++)
#pragma unroll
        for (int kk = 0; kk < 2; kk++)
            wA[mf][kk] = *(const half8v*)(Wcat + (grp * 32 + mf * 16 + l15) * 64 +
                                          kk * 32 + quad * 8);
    half8v xB[4][2];
#pragma unroll
    for (int nf = 0; nf < 4; nf++)
#pragma unroll
        for (int kk = 0; kk < 2; kk++)
            xB[nf][kk] = *(const half8v*)&sx[nf * 16 + l15][kk * 32 + quad * 8];

    f32x4 acc[2][4];
    const f32x4 z = {0.f, 0.f, 0.f, 0.f};
#pragma unroll
    for (int mf = 0; mf < 2; mf++)
#pragma unroll
        for (int nf = 0; nf < 4; nf++) {
            f32x4 a = __builtin_amdgcn_mfma_f32_16x16x32_f16(wA[mf][0], xB[nf][0], z, 0, 0, 0);
            acc[mf][nf] = __builtin_amdgcn_mfma_f32_16x16x32_f16(wA[mf][1], xB[nf][1], a, 0, 0, 0);
        }
#pragma unroll
    for (int mf = 0; mf < 2; mf++) {
        float4 bv = *(const float4*)&biasbuf[grp * 32 + mf * 16 + quad * 4];
#pragma unroll
        for (int nf = 0; nf < 4; nf++) {
            acc[mf][nf][0] += bv.x; acc[mf][nf][1] += bv.y;
            acc[mf][nf][2] += bv.z; acc[mf][nf][3] += bv.w;
        }
    }

    if (grp < 2) {
        half_t* F = (grp == 0) ? thfrag : phfrag;
#pragma unroll
        for (int mf = 0; mf < 2; mf++)
#pragma unroll
            for (int nf = 0; nf < 4; nf++) {
                half_t h[4];
                h[0] = (half_t)acc[mf][nf][0]; h[1] = (half_t)acc[mf][nf][1];
                h[2] = (half_t)acc[mf][nf][2]; h[3] = (half_t)acc[mf][nf][3];
                uint2 v;
                __builtin_memcpy(&v, h, 8);
                size_t u = (size_t)(b * 256 + (l0 >> 4) + nf) * 64 +
                           l15 + 16 * (mf * 2 + (quad >> 1));
                *(uint2*)(F + u * 8 + (quad & 1) * 4) = v;
            }
    } else {
#pragma unroll
        for (int mf = 0; mf < 2; mf++)
#pragma unroll
            for (int nf = 0; nf < 4; nf++)
#pragma unroll
                for (int r = 0; r < 4; r++) {
                    size_t u = (size_t)(b * 256 + (l0 >> 4) + nf) * 64 +
                               (quad * 4 + r) + 16 * (l15 >> 2);
                    gfrag[u * 8 + mf * 4 + (l15 & 3)] = f2bf(acc[mf][nf][r]);
                }
    }
}

// ---------------------------------------------------------------------------
// attn: LDS-staged flash attention. Per 64-key tile a block stages phi-frags
// (4KB) + g-frags (4KB) via global_load_lds (double-buffered); 4 waves each
// compute 32 q. S' = phi*theta^T (C-layout == K=16 PV B-layout -> packed exp2
// feeds PV directly, zero shuffles). Partials unnormalized.
// ---------------------------------------------------------------------------
__global__ __launch_bounds__(256, 4) void attn_kernel(
        const half_t* __restrict__ thfrag, const half_t* __restrict__ phfrag,
        const unsigned short* __restrict__ gfrag,
        unsigned short* __restrict__ part, float* __restrict__ Sden,
        int KC, int CH) {
    __shared__ uint4 sbuf[2][512];   // [buf][phi 4KB | g 4KB]

    int tid = threadIdx.x, lane = tid & 63, widx = tid >> 6;
    int l15 = lane & 15, quad = lane >> 4;

    int blk = blockIdx.x;
    int b = blk / (32 * KC);
    int rem = blk % (32 * KC);
    int qblk = rem / KC, kc = rem % KC;
    int qbase = qblk * 128 + widx * 32;
    int k0 = kc * CH;

    half8v th[2];
#pragma unroll
    for (int qf = 0; qf < 2; qf++)
        th[qf] = *(const half8v*)(thfrag +
                                  ((size_t)(b * 256 + (qbase >> 4) + qf) * 64 + lane) * 8);

    f32x4 acc[2][2];
#pragma unroll
    for (int qf = 0; qf < 2; qf++) {
        acc[qf][0] = (f32x4){0.f, 0.f, 0.f, 0.f};
        acc[qf][1] = (f32x4){0.f, 0.f, 0.f, 0.f};
    }
    float lsum[2] = {0.f, 0.f};

    const char* phsrc = (const char*)(phfrag + (size_t)b * 256 * 512);
    const char* gsrc  = (const char*)(gfrag + (size_t)b * 256 * 512);
    const f32x4 z = {0.f, 0.f, 0.f, 0.f};

    // prologue stage -> buf 0
    gll16(phsrc + (size_t)(k0 >> 4) * 1024 + tid * 16, (char*)&sbuf[0][0] + tid * 16);
    gll16(gsrc + (size_t)(k0 >> 4) * 1024 + tid * 16, (char*)&sbuf[0][256] + tid * 16);
    __syncthreads();

    int cb = 0;
    for (int kt = k0; kt < k0 + CH; kt += 64) {
        if (kt + 64 < k0 + CH) {
            gll16(phsrc + (size_t)((kt + 64) >> 4) * 1024 + tid * 16,
                  (char*)&sbuf[cb ^ 1][0] + tid * 16);
            gll16(gsrc + (size_t)((kt + 64) >> 4) * 1024 + tid * 16,
                  (char*)&sbuf[cb ^ 1][256] + tid * 16);
        }
        const half_t* sph = (const half_t*)&sbuf[cb][0];
        const unsigned short* sg = (const unsigned short*)&sbuf[cb][256];
#pragma unroll
        for (int kf = 0; kf < 4; kf++) {
            half8v phA = *(const half8v*)(sph + kf * 512 + lane * 8);
            short8v g8 = *(const short8v*)(sg + kf * 512 + lane * 8);
            short4v ga0 = __builtin_shufflevector(g8, g8, 0, 1, 2, 3);
            short4v ga1 = __builtin_shufflevector(g8, g8, 4, 5, 6, 7);
#pragma unroll
            for (int qf = 0; qf < 2; qf++) {
                f32x4 s = __builtin_amdgcn_mfma_f32_16x16x32_f16(phA, th[qf], z, 0, 0, 0);
                float p0 = __builtin_amdgcn_exp2f(s[0]);
                float p1 = __builtin_amdgcn_exp2f(s[1]);
                float p2 = __builtin_amdgcn_exp2f(s[2]);
                float p3 = __builtin_amdgcn_exp2f(s[3]);
                lsum[qf] += (p0 + p1) + (p2 + p3);
                union { short4v s4; uint2 u2; } pb;
                pb.u2.x = pack_bf(p0, p1);
                pb.u2.y = pack_bf(p2, p3);
                acc[qf][0] = __builtin_amdgcn_mfma_f32_16x16x16bf16_1k(ga0, pb.s4,
                                                                      acc[qf][0], 0, 0, 0);
                acc[qf][1] = __builtin_amdgcn_mfma_f32_16x16x16bf16_1k(ga1, pb.s4,
                                                                      acc[qf][1], 0, 0, 0);
            }
        }
        __syncthreads();
        cb ^= 1;
    }

#pragma unroll
    for (int qf = 0; qf < 2; qf++) {
        float v = lsum[qf];
        v += __shfl_xor(v, 16);
        v += __shfl_xor(v, 32);
        lsum[qf] = v;
    }
    size_t sb = (size_t)(b * KC + kc) * Ln + qbase;
    if (lane < 16) {
        Sden[sb + lane] = lsum[0];
        Sden[sb + 16 + lane] = lsum[1];
    }
    size_t pbase = (size_t)(b * KC + kc) * 32 * Ln;
#pragma unroll
    for (int qf = 0; qf < 2; qf++)
#pragma unroll
        for (int cf = 0; cf < 2; cf++)
#pragma unroll
            for (int r = 0; r < 4; r++) {
                int c = cf * 16 + quad * 4 + r;
                part[pbase + (size_t)c * Ln + qbase + qf * 16 + l15] =
                    f2bf(acc[qf][cf][r]);
            }
}

// ---------------------------------------------------------------------------
// merge1: ybar[b][j][l] = sum_kc part / sum_kc Sden, written as f16 B-frags
// [b][l16][lane][8] for merge2's MFMA. Grid 512 x 256.
// ---------------------------------------------------------------------------
__global__ __launch_bounds__(256) void merge1_kernel(
        const unsigned short* __restrict__ part, const float* __restrict__ Sden,
        half_t* __restrict__ ybar, int KC) {
    int t = blockIdx.x * 256 + threadIdx.x;
    int l4 = (t & 1023) << 2;
    int j = (t >> 10) & 31;
    int b = t >> 15;
    float num[4] = {0.f, 0.f, 0.f, 0.f};
    float den[4] = {0.f, 0.f, 0.f, 0.f};
    for (int kc = 0; kc < KC; kc++) {
        ushort4 y4 = *(const ushort4*)&part[((size_t)((b * KC + kc) * 32) + j) * Ln + l4];
        float4 lc = *(const float4*)&Sden[(size_t)(b * KC + kc) * Ln + l4];
        num[0] += bf2f(y4.x); num[1] += bf2f(y4.y);
        num[2] += bf2f(y4.z); num[3] += bf2f(y4.w);
        den[0] += lc.x; den[1] += lc.y; den[2] += lc.z; den[3] += lc.w;
    }
#pragma unroll
    for (int i = 0; i < 4; i++) {
        int l = l4 + i;
        size_t u = (size_t)(b * 256 + (l >> 4)) * 64 + (l & 15) + 16 * (j >> 3);
        ybar[u * 8 + (j & 7)] = (half_t)(num[i] / den[i]);
    }
}

// ---------------------------------------------------------------------------
// merge2: out[b][c][l] = W*ybar + W_b + x  via one 16x16x32 MFMA column.
// Grid Bn*64 x 256 (wave = one 16-l tile).
// ---------------------------------------------------------------------------
__global__ __launch_bounds__(256) void merge2_kernel(
        const half_t* __restrict__ ybar, const half_t* __restrict__ Wm,
        const float* __restrict__ bc, const float* __restrict__ x,
        float* __restrict__ out) {
    int tid = threadIdx.x, lane = tid & 63, widx = tid >> 6;
    int l15 = lane & 15, quad = lane >> 4;
    int b = blockIdx.x >> 6;
    int t16 = (blockIdx.x & 63) * 4 + widx;
    int l = (t16 << 4) + l15;

    half8v yB = *(const half8v*)(ybar + ((size_t)(b * 256 + t16) * 64 + lane) * 8);
    const f32x4 z = {0.f, 0.f, 0.f, 0.f};
    f32x4 acc[4];
#pragma unroll
    for (int mf = 0; mf < 4; mf++) {
        half8v wA = *(const half8v*)(Wm + (mf * 64 + lane) * 8);
        acc[mf] = __builtin_amdgcn_mfma_f32_16x16x32_f16(wA, yB, z, 0, 0, 0);
    }
#pragma unroll
    for (int mf = 0; mf < 4; mf++)
#pragma unroll
        for (int r = 0; r < 4; r++) {
            int c = mf * 16 + quad * 4 + r;
            size_t idx = (size_t)(b * 64 + c) * Ln + l;
            out[idx] = acc[mf][r] + bc[c] + x[idx];
        }
}

extern "C" void kernel_launch(void* const* d_in, const int* in_sizes, int n_in,
                              void* d_out, int out_size, void* d_ws, size_t ws_size,
                              hipStream_t stream) {
    const float* x    = (const float*)d_in[0];
    const float* g_w  = (const float*)d_in[1];
    const float* g_b  = (const float*)d_in[2];
    const float* th_w = (const float*)d_in[3];
    const float* th_b = (const float*)d_in[4];
    const float* ph_w = (const float*)d_in[5];
    const float* ph_b = (const float*)d_in[6];
    const float* W_w  = (const float*)d_in[7];
    const float* W_b  = (const float*)d_in[8];
    float* out = (float*)d_out;

    char* w = (char*)d_ws;
    const size_t off_th   = 0;                 // 1 MB  (4*256*64*8*2)
    const size_t off_ph   = 1048576;           // 1 MB
    const size_t off_g    = 2097152;           // 1 MB
    const size_t off_ybar = 3145728;           // 1 MB
    const size_t off_Wcat = 4194304;           // 12 KB
    const size_t off_bias = 4206592;           // 384 B
    const size_t off_bc   = 4207104;           // 256 B
    const size_t off_Wm   = 4207360;           // 4 KB
    const size_t off_Sden = 4211712;           // KC*4*4096*4

    int KC = 8;
    size_t off_part = 0;
    while (true) {
        off_part = off_Sden + (size_t)KC * (Bn * Ln * 4);
        off_part = (off_part + 255) & ~(size_t)255;
        size_t need = off_part + (size_t)KC * ((size_t)Bn * 32 * Ln * 2);
        if (need <= ws_size || KC == 1) break;
        KC >>= 1;
    }

    half_t* thfrag = (half_t*)(w + off_th);
    half_t* phfrag = (half_t*)(w + off_ph);
    unsigned short* gfrag = (unsigned short*)(w + off_g);
    half_t* ybar   = (half_t*)(w + off_ybar);
    half_t* Wcat   = (half_t*)(w + off_Wcat);
    float* biasbuf = (float*)(w + off_bias);
    float* bc      = (float*)(w + off_bc);
    half_t* Wm     = (half_t*)(w + off_Wm);
    float* Sden    = (float*)(w + off_Sden);
    unsigned short* part = (unsigned short*)(w + off_part);

    int CH = Ln / KC;

    setup_kernel<<<99, 64, 0, stream>>>(g_w, g_b, th_w, th_b, ph_w, ph_b, W_w, W_b,
                                        Wcat, biasbuf, bc, Wm);
    proj_kernel<<<Bn * 64, 192, 0, stream>>>(x, Wcat, biasbuf, thfrag, phfrag, gfrag);
    attn_kernel<<<Bn * 32 * KC, 256, 0, stream>>>(thfrag, phfrag, gfrag, part, Sden,
                                                  KC, CH);
    merge1_kernel<<<512, 256, 0, stream>>>(part, Sden, ybar, KC);
    merge2_kernel<<<Bn * 64, 256, 0, stream>>>(ybar, Wm, bc, x, out);
}

// Round 6
// 102.885 us; speedup vs baseline: 1.5385x; 1.0170x over previous
//
#include <hip/hip_runtime.h>

#define Bn 4
#define Cdim 64
#define INTER 32
#define Ln 4096
#define LOG2E 1.44269504088896340736f

typedef _Float16 half_t;
typedef __attribute__((ext_vector_type(8))) _Float16 half8v;
typedef __attribute__((ext_vector_type(4))) short short4v;
typedef __attribute__((ext_vector_type(8))) short short8v;
typedef __attribute__((ext_vector_type(4))) float f32x4;

__device__ __forceinline__ unsigned short f2bf(float f) {
    unsigned u = __float_as_uint(f);
    u += 0x7fffu + ((u >> 16) & 1u);
    return (unsigned short)(u >> 16);
}
__device__ __forceinline__ float bf2f(unsigned short b) {
    return __uint_as_float(((unsigned)b) << 16);
}
__device__ __forceinline__ unsigned pack_bf(float a, float b) {
    unsigned ua = __float_as_uint(a) + 0x8000u;
    unsigned ub = __float_as_uint(b) + 0x8000u;
    return __builtin_amdgcn_perm(ub, ua, 0x07060302);
}
__device__ __forceinline__ void gll16(const void* g, void* l) {
    __builtin_amdgcn_global_load_lds(
        (const __attribute__((address_space(1))) unsigned int*)g,
        (__attribute__((address_space(3))) unsigned int*)l, 16, 0, 0);
}

// ---------------------------------------------------------------------------
// setup: Wcat f16[96][64] = [th_w*log2e ; ph_w ; g_w]; biasbuf f32[96];
// bc f32[64] = W_b; Wm = W_w f16 in MFMA A-frag layout.
// ---------------------------------------------------------------------------
__global__ void setup_kernel(const float* __restrict__ g_w, const float* __restrict__ g_b,
                             const float* __restrict__ th_w, const float* __restrict__ th_b,
                             const float* __restrict__ ph_w, const float* __restrict__ ph_b,
                             const float* __restrict__ W_w, const float* __restrict__ W_b,
                             half_t* __restrict__ Wcat, float* __restrict__ biasbuf,
                             float* __restrict__ bc, half_t* __restrict__ Wm) {
    int blk = blockIdx.x, tid = threadIdx.x;
    if (blk < 96) {
        int row = blk;
        float v;
        if (row < 32) v = th_w[row * 64 + tid] * LOG2E;
        else if (row < 64) v = ph_w[(row - 32) * 64 + tid];
        else v = g_w[(row - 64) * 64 + tid];
        Wcat[row * 64 + tid] = (half_t)v;
    } else if (blk == 96) {
        for (int i = tid; i < 96; i += 64) {
            float v = (i < 32) ? th_b[i] * LOG2E : (i < 64) ? ph_b[i - 32] : g_b[i - 64];
            biasbuf[i] = v;
        }
    } else if (blk == 97) {
        bc[tid] = W_b[tid];
    } else {
        int l15 = tid & 15, jb = (tid >> 4) * 8;
        for (int mf = 0; mf < 4; mf++) {
            int c = mf * 16 + l15;
            half_t tmp[8];
            for (int j = 0; j < 8; j++) tmp[j] = (half_t)W_w[c * 32 + jb + j];
            float4 v;
            __builtin_memcpy(&v, tmp, 16);
            *(float4*)(Wm + (mf * 64 + tid) * 8) = v;
        }
    }
}

// ---------------------------------------------------------------------------
// proj (MFMA): [96ch][64l] = Wcat * x-tile. Grid Bn*64 x 192 (3 waves).
// Fragment-layout outputs; g staged through LDS -> coalesced 16B stores.
// ---------------------------------------------------------------------------
__global__ __launch_bounds__(192) void proj_kernel(
        const float* __restrict__ x, const half_t* __restrict__ Wcat,
        const float* __restrict__ biasbuf,
        half_t* __restrict__ thfrag, half_t* __restrict__ phfrag,
        unsigned short* __restrict__ gfrag) {
    __shared__ half_t sx[64][72];        // [l][c]
    __shared__ unsigned short sg[2048];  // g-frag staging (4KB)
    int tid = threadIdx.x;
    int b = blockIdx.x >> 6;
    int l0 = (blockIdx.x & 63) << 6;

    for (int i = tid; i < 1024; i += 192) {
        int c = i >> 4, lq = (i & 15) << 2;
        float4 v = *(const float4*)&x[(size_t)(b * 64 + c) * Ln + l0 + lq];
        sx[lq + 0][c] = (half_t)v.x;
        sx[lq + 1][c] = (half_t)v.y;
        sx[lq + 2][c] = (half_t)v.z;
        sx[lq + 3][c] = (half_t)v.w;
    }
    __syncthreads();

    int lane = tid & 63, grp = tid >> 6;    // 0=theta 1=phi 2=g
    int l15 = lane & 15, quad = lane >> 4;

    half8v wA[2][2];
#pragma unroll
    for (int mf = 0; mf < 2; mf++)
#pragma unroll
        for (int kk = 0; kk < 2; kk++)
            wA[mf][kk] = *(const half8v*)(Wcat + (grp * 32 + mf * 16 + l15) * 64 +
                                          kk * 32 + quad * 8);
    half8v xB[4][2];
#pragma unroll
    for (int nf = 0; nf < 4; nf++)
#pragma unroll
        for (int kk = 0; kk < 2; kk++)
            xB[nf][kk] = *(const half8v*)&sx[nf * 16 + l15][kk * 32 + quad * 8];

    f32x4 acc[2][4];
    const f32x4 z = {0.f, 0.f, 0.f, 0.f};
#pragma unroll
    for (int mf = 0; mf < 2; mf++)
#pragma unroll
        for (int nf = 0; nf < 4; nf++) {
            f32x4 a = __builtin_amdgcn_mfma_f32_16x16x32_f16(wA[mf][0], xB[nf][0], z, 0, 0, 0);
            acc[mf][nf] = __builtin_amdgcn_mfma_f32_16x16x32_f16(wA[mf][1], xB[nf][1], a, 0, 0, 0);
        }
#pragma unroll
    for (int mf = 0; mf < 2; mf++) {
        float4 bv = *(const float4*)&biasbuf[grp * 32 + mf * 16 + quad * 4];
#pragma unroll
        for (int nf = 0; nf < 4; nf++) {
            acc[mf][nf][0] += bv.x; acc[mf][nf][1] += bv.y;
            acc[mf][nf][2] += bv.z; acc[mf][nf][3] += bv.w;
        }
    }

    if (grp < 2) {
        half_t* F = (grp == 0) ? thfrag : phfrag;
#pragma unroll
        for (int mf = 0; mf < 2; mf++)
#pragma unroll
            for (int nf = 0; nf < 4; nf++) {
                half_t h[4];
                h[0] = (half_t)acc[mf][nf][0]; h[1] = (half_t)acc[mf][nf][1];
                h[2] = (half_t)acc[mf][nf][2]; h[3] = (half_t)acc[mf][nf][3];
                uint2 v;
                __builtin_memcpy(&v, h, 8);
                size_t u = (size_t)(b * 256 + (l0 >> 4) + nf) * 64 +
                           l15 + 16 * (mf * 2 + (quad >> 1));
                *(uint2*)(F + u * 8 + (quad & 1) * 4) = v;
            }
    } else {
        // stage g-frag tile in LDS (local index = global - block base)
#pragma unroll
        for (int mf = 0; mf < 2; mf++)
#pragma unroll
            for (int nf = 0; nf < 4; nf++)
#pragma unroll
                for (int r = 0; r < 4; r++) {
                    int lu = nf * 64 + (quad * 4 + r) + 16 * (l15 >> 2);
                    sg[lu * 8 + mf * 4 + (l15 & 3)] = f2bf(acc[mf][nf][r]);
                }
        __builtin_amdgcn_s_waitcnt(0);  // drain lgkm before re-reading own LDS
        size_t base = (size_t)(b * 256 + (l0 >> 4)) * 512;
#pragma unroll
        for (int s = 0; s < 4; s++) {
            int i = lane + s * 64;
            uint4 v = ((const uint4*)sg)[i];
            *(uint4*)(gfrag + base + (size_t)i * 8) = v;
        }
    }
}

// ---------------------------------------------------------------------------
// attn: LDS-staged flash attention; denominator computed on the MFMA pipe via
// a ones-row A-frag (row0 of an extra 16x16x16 accumulates sum_k P[k][q]).
// ---------------------------------------------------------------------------
__global__ __launch_bounds__(256, 4) void attn_kernel(
        const half_t* __restrict__ thfrag, const half_t* __restrict__ phfrag,
        const unsigned short* __restrict__ gfrag,
        unsigned short* __restrict__ part, float* __restrict__ Sden,
        int KC, int CH) {
    __shared__ uint4 sbuf[2][512];   // [buf][phi 4KB | g 4KB]

    int tid = threadIdx.x, lane = tid & 63, widx = tid >> 6;
    int l15 = lane & 15, quad = lane >> 4;

    int blk = blockIdx.x;
    int b = blk / (32 * KC);
    int rem = blk % (32 * KC);
    int qblk = rem / KC, kc = rem % KC;
    int qbase = qblk * 128 + widx * 32;
    int k0 = kc * CH;

    half8v th[2];
#pragma unroll
    for (int qf = 0; qf < 2; qf++)
        th[qf] = *(const half8v*)(thfrag +
                                  ((size_t)(b * 256 + (qbase >> 4) + qf) * 64 + lane) * 8);

    // ones A-frag: row m==0 is 1.0 (bf16), rest 0
    unsigned short oh = (l15 == 0) ? 0x3F80 : 0;
    short4v ones;
    ones[0] = (short)oh; ones[1] = (short)oh; ones[2] = (short)oh; ones[3] = (short)oh;

    f32x4 acc[2][2], accd[2];
#pragma unroll
    for (int qf = 0; qf < 2; qf++) {
        acc[qf][0] = (f32x4){0.f, 0.f, 0.f, 0.f};
        acc[qf][1] = (f32x4){0.f, 0.f, 0.f, 0.f};
        accd[qf]   = (f32x4){0.f, 0.f, 0.f, 0.f};
    }

    const char* phsrc = (const char*)(phfrag + (size_t)b * 256 * 512);
    const char* gsrc  = (const char*)(gfrag + (size_t)b * 256 * 512);
    const f32x4 z = {0.f, 0.f, 0.f, 0.f};

    gll16(phsrc + (size_t)(k0 >> 4) * 1024 + tid * 16, (char*)&sbuf[0][0] + tid * 16);
    gll16(gsrc + (size_t)(k0 >> 4) * 1024 + tid * 16, (char*)&sbuf[0][256] + tid * 16);
    __syncthreads();

    int cb = 0;
    for (int kt = k0; kt < k0 + CH; kt += 64) {
        if (kt + 64 < k0 + CH) {
            gll16(phsrc + (size_t)((kt + 64) >> 4) * 1024 + tid * 16,
                  (char*)&sbuf[cb ^ 1][0] + tid * 16);
            gll16(gsrc + (size_t)((kt + 64) >> 4) * 1024 + tid * 16,
                  (char*)&sbuf[cb ^ 1][256] + tid * 16);
        }
        const half_t* sph = (const half_t*)&sbuf[cb][0];
        const unsigned short* sg = (const unsigned short*)&sbuf[cb][256];
#pragma unroll
        for (int kf = 0; kf < 4; kf++) {
            half8v phA = *(const half8v*)(sph + kf * 512 + lane * 8);
            short8v g8 = *(const short8v*)(sg + kf * 512 + lane * 8);
            short4v ga0 = __builtin_shufflevector(g8, g8, 0, 1, 2, 3);
            short4v ga1 = __builtin_shufflevector(g8, g8, 4, 5, 6, 7);
#pragma unroll
            for (int qf = 0; qf < 2; qf++) {
                f32x4 s = __builtin_amdgcn_mfma_f32_16x16x32_f16(phA, th[qf], z, 0, 0, 0);
                float p0 = __builtin_amdgcn_exp2f(s[0]);
                float p1 = __builtin_amdgcn_exp2f(s[1]);
                float p2 = __builtin_amdgcn_exp2f(s[2]);
                float p3 = __builtin_amdgcn_exp2f(s[3]);
                union { short4v s4; uint2 u2; } pb;
                pb.u2.x = pack_bf(p0, p1);
                pb.u2.y = pack_bf(p2, p3);
                acc[qf][0] = __builtin_amdgcn_mfma_f32_16x16x16bf16_1k(ga0, pb.s4,
                                                                      acc[qf][0], 0, 0, 0);
                acc[qf][1] = __builtin_amdgcn_mfma_f32_16x16x16bf16_1k(ga1, pb.s4,
                                                                      acc[qf][1], 0, 0, 0);
                accd[qf] = __builtin_amdgcn_mfma_f32_16x16x16bf16_1k(ones, pb.s4,
                                                                    accd[qf], 0, 0, 0);
            }
        }
        __syncthreads();
        cb ^= 1;
    }

    // denominator lives in row 0 of accd -> lanes with quad==0, reg 0
    size_t sb = (size_t)(b * KC + kc) * Ln + qbase;
    if (quad == 0) {
        Sden[sb + l15] = accd[0][0];
        Sden[sb + 16 + l15] = accd[1][0];
    }
    size_t pbase = (size_t)(b * KC + kc) * 32 * Ln;
#pragma unroll
    for (int qf = 0; qf < 2; qf++)
#pragma unroll
        for (int cf = 0; cf < 2; cf++)
#pragma unroll
            for (int r = 0; r < 4; r++) {
                int c = cf * 16 + quad * 4 + r;
                part[pbase + (size_t)c * Ln + qbase + qf * 16 + l15] =
                    f2bf(acc[qf][cf][r]);
            }
}

// ---------------------------------------------------------------------------
// merge (fused): ybar = sum_kc part / sum_kc Sden in registers, then
// out[b][c][l] = W*ybar + W_b + x via 16x16x32 MFMA. Grid Bn*64 x 256.
// ---------------------------------------------------------------------------
__global__ __launch_bounds__(256) void merge_kernel(
        const unsigned short* __restrict__ part, const float* __restrict__ Sden,
        const half_t* __restrict__ Wm, const float* __restrict__ bc,
        const float* __restrict__ x, float* __restrict__ out, int KC) {
    int tid = threadIdx.x, lane = tid & 63, widx = tid >> 6;
    int l15 = lane & 15, quad = lane >> 4;
    int b = blockIdx.x >> 6;
    int t16 = (blockIdx.x & 63) * 4 + widx;
    int l = (t16 << 4) + l15;

    float den = 0.f;
    for (int kc = 0; kc < KC; kc++) den += Sden[(size_t)(b * KC + kc) * Ln + l];
    float inv = 1.f / den;

    float num[8] = {0.f, 0.f, 0.f, 0.f, 0.f, 0.f, 0.f, 0.f};
    for (int kc = 0; kc < KC; kc++) {
        size_t base = ((size_t)((b * KC + kc) * 32) + quad * 8) * Ln + l;
#pragma unroll
        for (int j = 0; j < 8; j++) num[j] += bf2f(part[base + (size_t)j * Ln]);
    }
    half_t yh[8];
#pragma unroll
    for (int j = 0; j < 8; j++) yh[j] = (half_t)(num[j] * inv);
    half8v yB;
    __builtin_memcpy(&yB, yh, 16);

    const f32x4 z = {0.f, 0.f, 0.f, 0.f};
    f32x4 acc[4];
#pragma unroll
    for (int mf = 0; mf < 4; mf++) {
        half8v wA = *(const half8v*)(Wm + (mf * 64 + lane) * 8);
        acc[mf] = __builtin_amdgcn_mfma_f32_16x16x32_f16(wA, yB, z, 0, 0, 0);
    }
#pragma unroll
    for (int mf = 0; mf < 4; mf++) {
        float4 bv = *(const float4*)&bc[mf * 16 + quad * 4];
#pragma unroll
        for (int r = 0; r < 4; r++) {
            int c = mf * 16 + quad * 4 + r;
            size_t idx = (size_t)(b * 64 + c) * Ln + l;
            float bb = (r == 0) ? bv.x : (r == 1) ? bv.y : (r == 2) ? bv.z : bv.w;
            out[idx] = acc[mf][r] + bb + x[idx];
        }
    }
}

extern "C" void kernel_launch(void* const* d_in, const int* in_sizes, int n_in,
                              void* d_out, int out_size, void* d_ws, size_t ws_size,
                              hipStream_t stream) {
    const float* x    = (const float*)d_in[0];
    const float* g_w  = (const float*)d_in[1];
    const float* g_b  = (const float*)d_in[2];
    const float* th_w = (const float*)d_in[3];
    const float* th_b = (const float*)d_in[4];
    const float* ph_w = (const float*)d_in[5];
    const float* ph_b = (const float*)d_in[6];
    const float* W_w  = (const float*)d_in[7];
    const float* W_b  = (const float*)d_in[8];
    float* out = (float*)d_out;

    char* w = (char*)d_ws;
    const size_t off_th   = 0;                 // 1 MB
    const size_t off_ph   = 1048576;           // 1 MB
    const size_t off_g    = 2097152;           // 1 MB
    const size_t off_Wcat = 4194304;           // 12 KB
    const size_t off_bias = 4206592;
    const size_t off_bc   = 4207104;
    const size_t off_Wm   = 4207360;
    const size_t off_Sden = 4211712;

    int KC = 8;
    size_t off_part = 0;
    while (true) {
        off_part = off_Sden + (size_t)KC * (Bn * Ln * 4);
        off_part = (off_part + 255) & ~(size_t)255;
        size_t need = off_part + (size_t)KC * ((size_t)Bn * 32 * Ln * 2);
        if (need <= ws_size || KC == 1) break;
        KC >>= 1;
    }

    half_t* thfrag = (half_t*)(w + off_th);
    half_t* phfrag = (half_t*)(w + off_ph);
    unsigned short* gfrag = (unsigned short*)(w + off_g);
    half_t* Wcat   = (half_t*)(w + off_Wcat);
    float* biasbuf = (float*)(w + off_bias);
    float* bc      = (float*)(w + off_bc);
    half_t* Wm     = (half_t*)(w + off_Wm);
    float* Sden    = (float*)(w + off_Sden);
    unsigned short* part = (unsigned short*)(w + off_part);

    int CH = Ln / KC;

    setup_kernel<<<99, 64, 0, stream>>>(g_w, g_b, th_w, th_b, ph_w, ph_b, W_w, W_b,
                                        Wcat, biasbuf, bc, Wm);
    proj_kernel<<<Bn * 64, 192, 0, stream>>>(x, Wcat, biasbuf, thfrag, phfrag, gfrag);
    attn_kernel<<<Bn * 32 * KC, 256, 0, stream>>>(thfrag, phfrag, gfrag, part, Sden,
                                                  KC, CH);
    merge_kernel<<<Bn * 64, 256, 0, stream>>>(part, Sden, Wm, bc, x, out, KC);
}